// Round 13
// baseline (4540.072 us; speedup 1.0000x reference)
//
#include <hip/hip_runtime.h>
#include <cstdint>
#include <cmath>

typedef unsigned short u16;
typedef unsigned int u32;
typedef __attribute__((ext_vector_type(8))) short bf16x8;
typedef __attribute__((ext_vector_type(4))) float f32x4;

// ---- model dims ----
#define B_    8
#define T_IN  2048
#define CIN1  273
#define L1_   1025
#define L_    513
#define C_    512
#define CE_   576
#define M1_   (B_*L1_)   /* 8200 */
#define M_    (B_*L_)    /* 4104 */
#define K1_   (CIN1*4)   /* 1092 */
#define H_    8
#define D_    64
#define R_    50

__device__ __forceinline__ u32 f2bf_rne(float f) {
    u32 x = __float_as_uint(f);
    return (x + 0x7fffu + ((x >> 16) & 1u)) >> 16;
}

// ======================= A-pair loader: returns packed bf16x2 for (k, k+1), k even ==============
// amode: 2 conv1 im2col from meg (fp32); 5 conv2 im2col from x1b (bf16, k-order kk*512+ci);
//        6 bf16 rowmajor(lda); 7 bf16 time-major [t*8+b][512]
__device__ __forceinline__ u32 a_pair(const void* A, int m, int k, int lda, int amode, int Ksz) {
    if (amode == 2) {
        if (k >= K1_) return 0;
        int b = m / L1_, t = m - b * L1_;
        int ci = k >> 2, kk = k & 3;
        int it = 2 * t - 2 + kk;
        const float* mg = (const float*)A + ((size_t)(b * CIN1 + ci)) * T_IN;
        u32 lo = ((unsigned)it < (unsigned)T_IN)       ? f2bf_rne(mg[it])     : 0;
        u32 hi = ((unsigned)(it + 1) < (unsigned)T_IN) ? f2bf_rne(mg[it + 1]) : 0;
        return lo | (hi << 16);
    } else if (amode == 5) {
        int b = m / L_, t = m - b * L_;
        int kk = k >> 9, ci = k & 511;
        int it = 2 * t - 2 + kk;
        if ((unsigned)it >= (unsigned)L1_) return 0;
        return *(const u32*)((const u16*)A + ((size_t)(b * L1_ + it)) * 512 + ci);
    } else if (amode == 6) {
        return *(const u32*)((const u16*)A + (size_t)m * lda + k);
    } else {
        int b = m / L_, t = m - b * L_;
        return *(const u32*)((const u16*)A + ((size_t)(t * 8 + b)) * 512 + k);
    }
}

// ======================= MFMA GEMM 64x64 (packed bf16 B) =======================
// cmode: 0 fp32 C[m*ldc+n]; 1 out[b][n][t] (n<128); 2 fp32 [(t*8+b)*ldc+n]; 3 bf16 Cb[m*ldc+n]
__global__ __launch_bounds__(256) void gemm_kernel(
    const void* __restrict__ Aptr, const u32* __restrict__ Bp,
    const float* __restrict__ bias1, const float* __restrict__ bias2,
    float* __restrict__ Cf, u16* __restrict__ Cb,
    int Msz, int Nsz, int Ksz, int lda, int ldc, int amode, int cmode, int relu)
{
    __shared__ u16 As[64][40];
    __shared__ u16 Bs[64][40];

    int tid = threadIdx.x;
    int m0 = blockIdx.x * 64, n0 = blockIdx.y * 64;
    int wv = tid >> 6, lane = tid & 63;
    int lm = lane & 15, quad = lane >> 4;
    int kp = tid & 15, rw = tid >> 4;
    int Kh = Ksz >> 1;

    f32x4 acc[4];
#pragma unroll
    for (int nt = 0; nt < 4; ++nt)
#pragma unroll
        for (int r = 0; r < 4; ++r) acc[nt][r] = 0.f;

    for (int k0 = 0; k0 < Ksz; k0 += 32) {
        int pidx = (k0 >> 1) + kp;
#pragma unroll
        for (int i = 0; i < 4; ++i) {
            int row = rw + 16 * i;
            int k = k0 + 2 * kp;
            int m = m0 + row;
            u32 aw = 0;
            if (m < Msz && k < Ksz) aw = a_pair(Aptr, m, k, lda, amode, Ksz);
            *(u32*)&As[row][2 * kp] = aw;
            u32 bw = 0;
            if (pidx < Kh) bw = Bp[(size_t)(n0 + row) * Kh + pidx];
            *(u32*)&Bs[row][2 * kp] = bw;
        }
        __syncthreads();

        bf16x8 af = *(const bf16x8*)&As[wv * 16 + lm][quad * 8];
#pragma unroll
        for (int nt = 0; nt < 4; ++nt) {
            bf16x8 bf = *(const bf16x8*)&Bs[nt * 16 + lm][quad * 8];
            acc[nt] = __builtin_amdgcn_mfma_f32_16x16x32_bf16(af, bf, acc[nt], 0, 0, 0);
        }
        __syncthreads();
    }

#pragma unroll
    for (int nt = 0; nt < 4; ++nt) {
#pragma unroll
        for (int r = 0; r < 4; ++r) {
            int m = m0 + wv * 16 + quad * 4 + r;
            if (m >= Msz) continue;
            int n = n0 + nt * 16 + lm;
            float v = acc[nt][r] + bias1[n] + (bias2 ? bias2[n] : 0.f);
            if (relu) v = fmaxf(v, 0.f);
            if (cmode == 0) {
                Cf[(size_t)m * ldc + n] = v;
            } else if (cmode == 1) {
                int b = m / L_, t = m - b * L_;
                Cf[((size_t)(b * 128 + n)) * L_ + t] = v;
            } else if (cmode == 2) {
                int b = m / L_, t = m - b * L_;
                Cf[((size_t)(t * 8 + b)) * ldc + n] = v;
            } else {
                Cb[(size_t)m * ldc + n] = (u16)f2bf_rne(v);
            }
        }
    }
}

// ======================= MFMA GEMM 128x128 (big tile) =======================
// Wave wv covers rows wv*32..wv*32+31 x all 128 cols: 2 A-frags x 8 B-frags = 16 MFMA/K-step.
__global__ __launch_bounds__(256) void gemm_big(
    const void* __restrict__ Aptr, const u32* __restrict__ Bp,
    const float* __restrict__ bias1, const float* __restrict__ bias2,
    float* __restrict__ Cf, u16* __restrict__ Cb,
    int Msz, int Ksz, int lda, int ldc, int amode, int cmode, int relu)
{
    __shared__ u16 As[128][40];
    __shared__ u16 Bs[128][40];

    int tid = threadIdx.x;
    int m0 = blockIdx.x * 128, n0 = blockIdx.y * 128;
    int wv = tid >> 6, lane = tid & 63;
    int lm = lane & 15, quad = lane >> 4;
    int kp = tid & 15, rw = tid >> 4;
    int Kh = Ksz >> 1;

    f32x4 acc[2][8];
#pragma unroll
    for (int a = 0; a < 2; ++a)
#pragma unroll
        for (int nt = 0; nt < 8; ++nt)
#pragma unroll
            for (int r = 0; r < 4; ++r) acc[a][nt][r] = 0.f;

    for (int k0 = 0; k0 < Ksz; k0 += 32) {
        int pidx = (k0 >> 1) + kp;
        int k = k0 + 2 * kp;
#pragma unroll
        for (int i = 0; i < 8; ++i) {
            int row = rw + 16 * i;
            int m = m0 + row;
            u32 aw = 0;
            if (m < Msz && k < Ksz) aw = a_pair(Aptr, m, k, lda, amode, Ksz);
            *(u32*)&As[row][2 * kp] = aw;
            u32 bw = 0;
            if (pidx < Kh) bw = Bp[(size_t)(n0 + row) * Kh + pidx];
            *(u32*)&Bs[row][2 * kp] = bw;
        }
        __syncthreads();

        bf16x8 af[2];
#pragma unroll
        for (int a = 0; a < 2; ++a)
            af[a] = *(const bf16x8*)&As[wv * 32 + a * 16 + lm][quad * 8];
#pragma unroll
        for (int nt = 0; nt < 8; ++nt) {
            bf16x8 bf = *(const bf16x8*)&Bs[nt * 16 + lm][quad * 8];
#pragma unroll
            for (int a = 0; a < 2; ++a)
                acc[a][nt] = __builtin_amdgcn_mfma_f32_16x16x32_bf16(af[a], bf, acc[a][nt], 0, 0, 0);
        }
        __syncthreads();
    }

#pragma unroll
    for (int a = 0; a < 2; ++a) {
#pragma unroll
        for (int nt = 0; nt < 8; ++nt) {
#pragma unroll
            for (int r = 0; r < 4; ++r) {
                int m = m0 + wv * 32 + a * 16 + quad * 4 + r;
                if (m >= Msz) continue;
                int n = n0 + nt * 16 + lm;
                float v = acc[a][nt][r] + bias1[n] + (bias2 ? bias2[n] : 0.f);
                if (relu) v = fmaxf(v, 0.f);
                if (cmode == 0) {
                    Cf[(size_t)m * ldc + n] = v;
                } else if (cmode == 2) {
                    int b = m / L_, t = m - b * L_;
                    Cf[((size_t)(t * 8 + b)) * ldc + n] = v;
                } else {
                    Cb[(size_t)m * ldc + n] = (u16)f2bf_rne(v);
                }
            }
        }
    }
}

// ======================= fused q/k/cnt projection GEMM (bf16 h1b A, packed B) ==================
__global__ __launch_bounds__(256) void gemm_qkv(
    const u16* __restrict__ h1b,
    const u32* __restrict__ qwp, const u32* __restrict__ kwp, const u32* __restrict__ cwp,
    const float* __restrict__ qb, const float* __restrict__ kb, const float* __restrict__ cb,
    float* __restrict__ qo, float* __restrict__ ko, float* __restrict__ co)
{
    __shared__ u16 As[64][40];
    __shared__ u16 Bs[64][40];

    int tid = threadIdx.x;
    int which = blockIdx.y >> 3;
    int m0 = blockIdx.x * 64, n0 = (blockIdx.y & 7) * 64;
    const u32* Bp = which == 0 ? qwp : (which == 1 ? kwp : cwp);
    const float* bias = which == 0 ? qb : (which == 1 ? kb : cb);
    float* Cf = which == 0 ? qo : (which == 1 ? ko : co);

    int wv = tid >> 6, lane = tid & 63;
    int lm = lane & 15, quad = lane >> 4;
    int kp = tid & 15, rw = tid >> 4;

    f32x4 acc[4];
#pragma unroll
    for (int nt = 0; nt < 4; ++nt)
#pragma unroll
        for (int r = 0; r < 4; ++r) acc[nt][r] = 0.f;

    for (int k0 = 0; k0 < 512; k0 += 32) {
#pragma unroll
        for (int i = 0; i < 4; ++i) {
            int row = rw + 16 * i;
            int k = k0 + 2 * kp;
            int m = m0 + row;
            u32 aw = 0;
            if (m < M_) {
                int b = m / L_, t = m - b * L_;
                aw = *(const u32*)(h1b + ((size_t)(t * 8 + b)) * 512 + k);
            }
            *(u32*)&As[row][2 * kp] = aw;
            *(u32*)&Bs[row][2 * kp] = Bp[(size_t)(n0 + row) * 256 + (k0 >> 1) + kp];
        }
        __syncthreads();

        bf16x8 af = *(const bf16x8*)&As[wv * 16 + lm][quad * 8];
#pragma unroll
        for (int nt = 0; nt < 4; ++nt) {
            bf16x8 bf = *(const bf16x8*)&Bs[nt * 16 + lm][quad * 8];
            acc[nt] = __builtin_amdgcn_mfma_f32_16x16x32_bf16(af, bf, acc[nt], 0, 0, 0);
        }
        __syncthreads();
    }

#pragma unroll
    for (int nt = 0; nt < 4; ++nt) {
#pragma unroll
        for (int r = 0; r < 4; ++r) {
            int m = m0 + wv * 16 + quad * 4 + r;
            if (m >= M_) continue;
            int n = n0 + nt * 16 + lm;
            Cf[(size_t)m * 512 + n] = acc[nt][r] + bias[n];
        }
    }
}

// ======================= subject embedding concat (bf16) =======================
__global__ __launch_bounds__(256) void emb_kernel(const float* __restrict__ semb,
                                                  const int* __restrict__ subj,
                                                  u16* __restrict__ x2b)
{
    int idx = blockIdx.x * 256 + threadIdx.x;
    if (idx >= M_ * 64) return;
    int m = idx >> 6, e = idx & 63;
    int b = m / L_;
    x2b[(size_t)m * CE_ + 512 + e] = (u16)f2bf_rne(semb[subj[b] * 64 + e]);
}

// ======================= generic weight pack: fp32 [N][K] -> bf16 pairs [N][K/2] ================
__global__ __launch_bounds__(256) void pack_b(const float* __restrict__ W, u32* __restrict__ P,
                                              int N, int K)
{
    int gid = blockIdx.x * 256 + threadIdx.x;
    int Kh = K >> 1;
    if (gid >= N * Kh) return;
    int n = gid / Kh, p = gid - n * Kh;
    int k = 2 * p;
    u32 lo = f2bf_rne(W[(size_t)n * K + k]);
    u32 hi = f2bf_rne(W[(size_t)n * K + k + 1]);
    P[gid] = lo | (hi << 16);
}

// ======================= w2 pack with k-reorder: k' = kk*512 + ci =======================
__global__ __launch_bounds__(256) void pack_w2k(const float* __restrict__ W, u32* __restrict__ P)
{
    int gid = blockIdx.x * 256 + threadIdx.x;   // 512*1024
    int n = gid >> 10, p = gid & 1023;
    int kk = p >> 8, ci = (2 * p) & 511;
    u32 lo = f2bf_rne(W[(size_t)n * 2048 + ci * 4 + kk]);
    u32 hi = f2bf_rne(W[(size_t)n * 2048 + ci * 4 + 4 + kk]);
    P[gid] = lo | (hi << 16);
}

// ======================= LSTM weight pack =======================
__global__ __launch_bounds__(256) void pack_w(const float* __restrict__ W, u32* __restrict__ P)
{
    int gid = blockIdx.x * 256 + threadIdx.x;   // 524288 total
    int r = gid & 1, lane = (gid >> 1) & 63, i2 = (gid >> 7) & 1;
    int g = (gid >> 8) & 3, j = gid >> 10;
    int row = g * 512 + j;
    int c0 = 4 * (lane + 64 * i2) + 2 * r;
    u32 lo = f2bf_rne(W[(size_t)row * 512 + c0]);
    u32 hi = f2bf_rne(W[(size_t)row * 512 + c0 + 1]);
    P[gid] = lo | (hi << 16);
}

// ======================= fused 2-layer LSTM step (R10 structure + h1b mirror) ==================
__global__ __launch_bounds__(256, 1) void lstm_step_fused(
    const float* __restrict__ pre0,
    const u32* __restrict__ P0,
    const u32* __restrict__ P1,
    const u32* __restrict__ P2,
    const float* __restrict__ bih1,
    const float* __restrict__ bhh1,
    float* __restrict__ h0seq,
    float* __restrict__ h1seq,
    u16* __restrict__ h1b,
    float* __restrict__ c0st, float* __restrict__ c1st,
    int t)
{
    int layer = blockIdx.x >> 7;
    int blk = blockIdx.x & 127;
    if (layer == 0 && t >= L_) return;
    if (layer == 1 && t == 0) return;
    int tt = layer ? (t - 1) : t;

    int tid = threadIdx.x;
    int l  = tid & 63;
    int rg = tid >> 6;
    int j = blk * 4 + rg;

    __shared__ float4 hA4[1024];
    __shared__ float4 hB4[1024];
    __shared__ float part[4 * 8 * 33];
    __shared__ float gates[4 * 33];

    const u32* wA = (layer ? P2 : P0) + (size_t)j * 1024;
    uint2 wra[8], wrb[8];
#pragma unroll
    for (int i2 = 0; i2 < 2; ++i2)
#pragma unroll
        for (int g = 0; g < 4; ++g)
            wra[i2 * 4 + g] = *(const uint2*)&wA[(g * 2 + i2) * 128 + l * 2];
    if (layer) {
        const u32* wB = P1 + (size_t)j * 1024;
#pragma unroll
        for (int i2 = 0; i2 < 2; ++i2)
#pragma unroll
            for (int g = 0; g < 4; ++g)
                wrb[i2 * 4 + g] = *(const uint2*)&wB[(g * 2 + i2) * 128 + l * 2];
    }
    float mypre = 0.f;
    if (tid < 128) {
        int fw = tid >> 5, fb = tid & 7;
        int grow = ((tid & 31) >> 3) * 512 + blk * 4 + fw;
        mypre = layer ? (bih1[grow] + bhh1[grow])
                      : pre0[((size_t)(tt * 8 + fb)) * 2048 + grow];
    }

    if (tt == 0) {
#pragma unroll
        for (int i = 0; i < 4; ++i)
            hA4[tid + 256 * i] = make_float4(0.f, 0.f, 0.f, 0.f);
    } else {
        const float4* src = (const float4*)((layer ? h1seq : h0seq) + (size_t)(tt - 1) * 4096);
#pragma unroll
        for (int i = 0; i < 4; ++i)
            hA4[tid + 256 * i] = src[tid + 256 * i];
    }
    if (layer) {
        const float4* src = (const float4*)(h0seq + (size_t)tt * 4096);
#pragma unroll
        for (int i = 0; i < 4; ++i)
            hB4[tid + 256 * i] = src[tid + 256 * i];
    }
    __syncthreads();

    float acc[4][8];
#pragma unroll
    for (int g = 0; g < 4; ++g)
#pragma unroll
        for (int b = 0; b < 8; ++b) acc[g][b] = 0.f;

#pragma unroll
    for (int i2 = 0; i2 < 2; ++i2) {
        int cq = l + 64 * i2;
        float4 hv[8];
#pragma unroll
        for (int b = 0; b < 8; ++b) hv[b] = hA4[b * 128 + cq];
#pragma unroll
        for (int g = 0; g < 4; ++g) {
            uint2 ww = wra[i2 * 4 + g];
            float w0 = __uint_as_float(ww.x << 16);
            float w1 = __uint_as_float(ww.x & 0xffff0000u);
            float w2 = __uint_as_float(ww.y << 16);
            float w3 = __uint_as_float(ww.y & 0xffff0000u);
#pragma unroll
            for (int b = 0; b < 8; ++b)
                acc[g][b] = fmaf(w0, hv[b].x, fmaf(w1, hv[b].y,
                            fmaf(w2, hv[b].z, fmaf(w3, hv[b].w, acc[g][b]))));
        }
    }
    if (layer) {
#pragma unroll
        for (int i2 = 0; i2 < 2; ++i2) {
            int cq = l + 64 * i2;
            float4 hv[8];
#pragma unroll
            for (int b = 0; b < 8; ++b) hv[b] = hB4[b * 128 + cq];
#pragma unroll
            for (int g = 0; g < 4; ++g) {
                uint2 ww = wrb[i2 * 4 + g];
                float w0 = __uint_as_float(ww.x << 16);
                float w1 = __uint_as_float(ww.x & 0xffff0000u);
                float w2 = __uint_as_float(ww.y << 16);
                float w3 = __uint_as_float(ww.y & 0xffff0000u);
#pragma unroll
                for (int b = 0; b < 8; ++b)
                    acc[g][b] = fmaf(w0, hv[b].x, fmaf(w1, hv[b].y,
                                fmaf(w2, hv[b].z, fmaf(w3, hv[b].w, acc[g][b]))));
            }
        }
    }

#pragma unroll
    for (int m = 8; m <= 32; m <<= 1)
#pragma unroll
        for (int g = 0; g < 4; ++g)
#pragma unroll
            for (int b = 0; b < 8; ++b)
                acc[g][b] += __shfl_xor(acc[g][b], m);
    if (l < 8) {
#pragma unroll
        for (int g = 0; g < 4; ++g)
#pragma unroll
            for (int b = 0; b < 8; ++b)
                part[(rg * 8 + l) * 33 + g * 8 + b] = acc[g][b];
    }
    __syncthreads();

    if (tid < 128) {
        int w = tid >> 5, x = tid & 31;
        float s = 0.f;
#pragma unroll
        for (int p = 0; p < 8; ++p) s += part[(w * 8 + p) * 33 + x];
        gates[w * 33 + x] = s + mypre;
    }
    __syncthreads();

    if (tid < 32) {
        int w = tid >> 3, b = tid & 7;
        float gi = gates[w * 33 + 0 * 8 + b];
        float gf = gates[w * 33 + 1 * 8 + b];
        float gg = gates[w * 33 + 2 * 8 + b];
        float go = gates[w * 33 + 3 * 8 + b];
        float* cst = layer ? c1st : c0st;
        int ji = blk * 4 + w;
        int ci = b * 512 + ji;
        float cprev = (tt == 0) ? 0.f : cst[ci];
        float si = 1.f / (1.f + expf(-gi));
        float sf = 1.f / (1.f + expf(-gf));
        float so = 1.f / (1.f + expf(-go));
        float cn = sf * cprev + si * tanhf(gg);
        cst[ci] = cn;
        float hv = so * tanhf(cn);
        float* hout = layer ? h1seq : h0seq;
        hout[((size_t)tt * 8 + b) * 512 + ji] = hv;
        if (layer) h1b[((size_t)tt * 8 + b) * 512 + ji] = (u16)f2bf_rne(hv);
    }
}

// ======================= banded attention (radius 50), bf16 out =======================
__global__ __launch_bounds__(128) void attn_kernel(const float* __restrict__ q,
                                                   const float* __restrict__ k,
                                                   const float* __restrict__ cnt,
                                                   const float* __restrict__ rel,
                                                   u16* __restrict__ outb)
{
    int t = blockIdx.x, h = blockIdx.y, b = blockIdx.z;
    int s_lo = max(0, t - R_), s_hi = min(L_ - 1, t + R_);
    int W = s_hi - s_lo + 1;
    int tid = threadIdx.x;

    __shared__ float qrow[64];
    __shared__ float dots[104];
    __shared__ float red[128];

    const float* qp = q + ((size_t)(b * L_ + t) * C_ + h * D_);
    if (tid < 64) qrow[tid] = qp[tid];
    __syncthreads();

    if (tid < W) {
        int s = s_lo + tid;
        const float* kp = k + ((size_t)(b * L_ + s) * C_ + h * D_);
        const float* rp = rel + (R_ + t - s) * D_;
        float acc = 0.f;
#pragma unroll 8
        for (int d = 0; d < 64; ++d)
            acc += qrow[d] * (kp[d] + 0.3f * rp[d]);
        dots[tid] = acc;
    }
    __syncthreads();

    red[tid] = (tid < W) ? dots[tid] : -INFINITY;
    __syncthreads();
    for (int s = 64; s > 0; s >>= 1) {
        if (tid < s) red[tid] = fmaxf(red[tid], red[tid + s]);
        __syncthreads();
    }
    float mx = red[0];
    __syncthreads();
    float e = 0.f;
    if (tid < W) { e = expf(dots[tid] - mx); dots[tid] = e; }
    red[tid] = e;
    __syncthreads();
    for (int s = 64; s > 0; s >>= 1) {
        if (tid < s) red[tid] += red[tid + s];
        __syncthreads();
    }
    float inv = 1.f / red[0];
    if (tid < W) dots[tid] *= inv;
    __syncthreads();

    if (tid < 64) {
        float acc = 0.f;
        const float* cb = cnt + ((size_t)(b * L_ + s_lo) * C_ + h * D_ + tid);
        const float* rb = rel + (R_ + t - s_lo) * D_ + tid;
        for (int i = 0; i < W; ++i)
            acc += dots[i] * (cb[(size_t)i * C_] + 0.3f * rb[-i * D_]);
        outb[(size_t)(b * L_ + t) * C_ + h * D_ + tid] = (u16)f2bf_rne(acc);
    }
}

// ======================= BatchNorm sums (coalesced, atomic) =======================
__global__ __launch_bounds__(512) void bn_sum(const float* __restrict__ fcout, float* __restrict__ stats)
{
    int c = threadIdx.x;
    float s = 0.f, ss = 0.f;
    for (int m = blockIdx.x; m < M_; m += 32) {
        float v = fcout[(size_t)m * 512 + c];
        s += v; ss += v * v;
    }
    atomicAdd(&stats[c], s);
    atomicAdd(&stats[512 + c], ss);
}

// ======================= BN apply + ReLU*scale + residual -> bf16 xfin =======================
__global__ __launch_bounds__(256) void bn_apply(const float* __restrict__ fcout,
                                                const float* __restrict__ stats,
                                                const float* __restrict__ bng, const float* __restrict__ bnb,
                                                const float* __restrict__ ascl,
                                                const float* __restrict__ h1tm,
                                                u16* __restrict__ xfinb)
{
    int idx = blockIdx.x * 256 + threadIdx.x;
    if (idx >= M_ * 512) return;
    int c = idx & 511;
    int m = idx >> 9;
    int b = m / L_, t = m - b * L_;
    float mean = stats[c] * (1.f / (float)M_);
    float var = stats[512 + c] * (1.f / (float)M_) - mean * mean;
    float rs = rsqrtf(fmaxf(var, 0.f) + 1e-5f);
    float v = (fcout[idx] - mean) * rs * bng[c] + bnb[c];
    v = fmaxf(v, 0.f) * ascl[c];
    xfinb[idx] = (u16)f2bf_rne(h1tm[((size_t)(t * 8 + b)) * 512 + c] + v);
}

// ======================= host launch =======================
extern "C" void kernel_launch(void* const* d_in, const int* in_sizes, int n_in,
                              void* d_out, int out_size, void* d_ws, size_t ws_size,
                              hipStream_t stream)
{
    const float* meg  = (const float*)d_in[0];
    const float* w1   = (const float*)d_in[1];
    const float* b1   = (const float*)d_in[2];
    const float* w2   = (const float*)d_in[3];
    const float* b2   = (const float*)d_in[4];
    const float* semb = (const float*)d_in[5];
    const float* Wih0 = (const float*)d_in[6];
    const float* Whh0 = (const float*)d_in[7];
    const float* bih0 = (const float*)d_in[8];
    const float* bhh0 = (const float*)d_in[9];
    const float* Wih1 = (const float*)d_in[10];
    const float* Whh1 = (const float*)d_in[11];
    const float* bih1 = (const float*)d_in[12];
    const float* bhh1 = (const float*)d_in[13];
    const float* qw   = (const float*)d_in[14];
    const float* qb   = (const float*)d_in[15];
    const float* kw   = (const float*)d_in[16];
    const float* kb   = (const float*)d_in[17];
    const float* cw   = (const float*)d_in[18];
    const float* cbi  = (const float*)d_in[19];
    const float* rel  = (const float*)d_in[20];
    const float* fcw  = (const float*)d_in[21];
    const float* fcb  = (const float*)d_in[22];
    const float* bng  = (const float*)d_in[23];
    const float* bnb  = (const float*)d_in[24];
    const float* ascl = (const float*)d_in[25];
    const float* outw = (const float*)d_in[26];
    const float* outb = (const float*)d_in[27];
    const int* subj = (const int*)d_in[28];
    float* out = (float*)d_out;

    float* ws = (float*)d_ws;
    // ---- arena (float-slot offsets), phase-overlaid ----
    // conv phase:
    u16*   x1b   = (u16*)(ws + 0);          // [8200][512] bf16
    u32*   w1p   = (u32*)(ws + 6562304);    // 512x546
    u32*   w2p   = (u32*)(ws + 6841856);    // 512x1024
    u16*   x2b   = (u16*)(ws + 4198400);    // [4104][576] bf16
    u32*   wih0p = (u32*)(ws + 14967296);   // 2048x288
    // LSTM phase:
    u32*   P0    = (u32*)(ws + 0);
    u32*   P1    = (u32*)(ws + 524288);
    u32*   P2    = (u32*)(ws + 1048576);
    float* c0    = ws + 1572864;
    float* c1    = ws + 1576960;
    float* pre0  = ws + 6562304;            // [(t*8+b)][2048] fp32
    float* h0    = ws + 14967296;           // [t][b][c] fp32
    float* h1    = ws + 17068544;
    u16*   h1b   = (u16*)(ws + 19169792);   // bf16 mirror
    // post-LSTM phase:
    float* qb_f  = ws + 0;
    float* kb_f  = ws + 2101248;
    float* cb_f  = ws + 4202496;
    u16*   attno = (u16*)(ws + 6562304);    // bf16, over dead pre0
    float* fco   = ws + 8663552;
    float* stats = ws + 10764800;
    u32*   qwp   = (u32*)(ws + 10765824);
    u32*   kwp   = (u32*)(ws + 10896896);
    u32*   cwp   = (u32*)(ws + 11027968);
    u32*   fcwp  = (u32*)(ws + 11159040);
    u32*   outwp = (u32*)(ws + 11290112);
    u16*   xfinb = (u16*)(ws + 19169792);   // bf16, overwrites dead h1b

    auto gemm = [&](const void* A, const u32* Bp, const float* bi1, const float* bi2,
                    float* Cf, u16* Cb, int Msz, int Nsz, int Ksz,
                    int lda, int ldc, int amode, int cmode, int relu) {
        dim3 g((Msz + 63) / 64, Nsz / 64);
        gemm_kernel<<<g, 256, 0, stream>>>(A, Bp, bi1, bi2, Cf, Cb,
                                           Msz, Nsz, Ksz, lda, ldc, amode, cmode, relu);
    };
    auto gemmB = [&](const void* A, const u32* Bp, const float* bi1, const float* bi2,
                     float* Cf, u16* Cb, int Msz, int Nsz, int Ksz,
                     int lda, int ldc, int amode, int cmode, int relu) {
        dim3 g((Msz + 127) / 128, Nsz / 128);
        gemm_big<<<g, 256, 0, stream>>>(A, Bp, bi1, bi2, Cf, Cb,
                                        Msz, Ksz, lda, ldc, amode, cmode, relu);
    };

    // ---- pack conv weights ----
    pack_b<<<(512 * 546 + 255) / 256, 256, 0, stream>>>(w1, w1p, 512, 1092);
    pack_w2k<<<2048, 256, 0, stream>>>(w2, w2p);

    // conv1 -> x1b bf16 [b*1025+t][512], relu (128x128 tiles)
    gemmB(meg, w1p, b1, nullptr, nullptr, x1b, M1_, 512, K1_, 0, 512, 2, 3, 1);
    // conv2 -> x2b bf16 [b*513+t][576] cols 0..511, relu
    gemmB(x1b, w2p, b2, nullptr, nullptr, x2b, M_, 512, 2048, 0, CE_, 5, 3, 1);
    // subject embedding bf16 -> cols 512..575
    emb_kernel<<<(M_ * 64 + 255) / 256, 256, 0, stream>>>(semb, subj, x2b);

    // ---- pack LSTM + pre0 weights ----
    pack_w<<<2048, 256, 0, stream>>>(Whh0, P0);
    pack_w<<<2048, 256, 0, stream>>>(Wih1, P1);
    pack_w<<<2048, 256, 0, stream>>>(Whh1, P2);
    pack_b<<<(2048 * 288 + 255) / 256, 256, 0, stream>>>(Wih0, wih0p, 2048, 576);

    // layer-0 x-projection (bf16 A, packed B, time-major fp32 out, both biases)
    gemmB(x2b, wih0p, bih0, bhh0, pre0, nullptr, M_, 2048, CE_, CE_, 2048, 6, 2, 0);

    // fused 2-layer LSTM: 514 launches
    for (int t = 0; t <= L_; ++t)
        lstm_step_fused<<<256, 256, 0, stream>>>(pre0, P0, P1, P2, bih1, bhh1,
                                                 h0, h1, h1b, c0, c1, t);

    // ---- pack post weights ----
    pack_b<<<512, 256, 0, stream>>>(qw, qwp, 512, 512);
    pack_b<<<512, 256, 0, stream>>>(kw, kwp, 512, 512);
    pack_b<<<512, 256, 0, stream>>>(cw, cwp, 512, 512);
    pack_b<<<512, 256, 0, stream>>>(fcw, fcwp, 512, 512);
    pack_b<<<128, 256, 0, stream>>>(outw, outwp, 128, 512);
    hipMemsetAsync(stats, 0, 1024 * sizeof(float), stream);

    // fused q/k/cnt projections (bf16 h1b)
    gemm_qkv<<<dim3((M_ + 63) / 64, 24), 256, 0, stream>>>(h1b, qwp, kwp, cwp, qb, kb, cbi,
                                                           qb_f, kb_f, cb_f);

    attn_kernel<<<dim3(L_, H_, B_), 128, 0, stream>>>(qb_f, kb_f, cb_f, rel, attno);

    // fc (bf16 attno A) + BN(train) + relu*scale + residual -> xfinb bf16
    gemmB(attno, fcwp, fcb, nullptr, fco, nullptr, M_, 512, 512, 512, 512, 6, 0, 0);
    bn_sum<<<32, 512, 0, stream>>>(fco, stats);
    bn_apply<<<(M_ * 512 + 255) / 256, 256, 0, stream>>>(fco, stats, bng, bnb, ascl, h1, xfinb);

    // final projection -> d_out [b][128][t] fp32 (bf16 xfin A)
    gemm(xfinb, outwp, outb, nullptr, out, nullptr, M_, 128, 512, 512, 0, 6, 1, 0);
}

// Round 14
// 4291.476 us; speedup vs baseline: 1.0579x; 1.0579x over previous
//
#include <hip/hip_runtime.h>
#include <cstdint>
#include <cmath>

typedef unsigned short u16;
typedef unsigned int u32;
typedef __attribute__((ext_vector_type(8))) short bf16x8;
typedef __attribute__((ext_vector_type(4))) float f32x4;

// ---- model dims ----
#define B_    8
#define T_IN  2048
#define CIN1  273
#define L1_   1025
#define L_    513
#define C_    512
#define CE_   576
#define M1_   (B_*L1_)   /* 8200 */
#define M_    (B_*L_)    /* 4104 */
#define K1_   (CIN1*4)   /* 1092 */
#define H_    8
#define D_    64
#define R_    50

__device__ __forceinline__ u32 f2bf_rne(float f) {
    u32 x = __float_as_uint(f);
    return (x + 0x7fffu + ((x >> 16) & 1u)) >> 16;
}

// ======================= A-pair loader: returns packed bf16x2 for (k, k+1), k even ==============
// amode: 2 conv1 im2col from meg (fp32); 5 conv2 im2col from x1b (bf16, k-order kk*512+ci);
//        6 bf16 rowmajor(lda)
__device__ __forceinline__ u32 a_pair(const void* A, int m, int k, int lda, int amode, int Ksz) {
    if (amode == 2) {
        if (k >= K1_) return 0;
        int b = m / L1_, t = m - b * L1_;
        int ci = k >> 2, kk = k & 3;
        int it = 2 * t - 2 + kk;
        const float* mg = (const float*)A + ((size_t)(b * CIN1 + ci)) * T_IN;
        u32 lo = ((unsigned)it < (unsigned)T_IN)       ? f2bf_rne(mg[it])     : 0;
        u32 hi = ((unsigned)(it + 1) < (unsigned)T_IN) ? f2bf_rne(mg[it + 1]) : 0;
        return lo | (hi << 16);
    } else if (amode == 5) {
        int b = m / L_, t = m - b * L_;
        int kk = k >> 9, ci = k & 511;
        int it = 2 * t - 2 + kk;
        if ((unsigned)it >= (unsigned)L1_) return 0;
        return *(const u32*)((const u16*)A + ((size_t)(b * L1_ + it)) * 512 + ci);
    } else {
        return *(const u32*)((const u16*)A + (size_t)m * lda + k);
    }
}

// ======================= MFMA GEMM 64x64 (packed bf16 B) =======================
// cmode: 0 fp32 C[m*ldc+n]; 1 out[b][n][t] (n<128); 2 fp32 [(t*8+b)*ldc+n]; 3 bf16 Cb[m*ldc+n]
__global__ __launch_bounds__(256) void gemm_kernel(
    const void* __restrict__ Aptr, const u32* __restrict__ Bp,
    const float* __restrict__ bias1, const float* __restrict__ bias2,
    float* __restrict__ Cf, u16* __restrict__ Cb,
    int Msz, int Nsz, int Ksz, int lda, int ldc, int amode, int cmode, int relu)
{
    __shared__ u16 As[64][40];
    __shared__ u16 Bs[64][40];

    int tid = threadIdx.x;
    int m0 = blockIdx.x * 64, n0 = blockIdx.y * 64;
    int wv = tid >> 6, lane = tid & 63;
    int lm = lane & 15, quad = lane >> 4;
    int kp = tid & 15, rw = tid >> 4;
    int Kh = Ksz >> 1;

    f32x4 acc[4];
#pragma unroll
    for (int nt = 0; nt < 4; ++nt)
#pragma unroll
        for (int r = 0; r < 4; ++r) acc[nt][r] = 0.f;

    for (int k0 = 0; k0 < Ksz; k0 += 32) {
        int pidx = (k0 >> 1) + kp;
#pragma unroll
        for (int i = 0; i < 4; ++i) {
            int row = rw + 16 * i;
            int k = k0 + 2 * kp;
            int m = m0 + row;
            u32 aw = 0;
            if (m < Msz && k < Ksz) aw = a_pair(Aptr, m, k, lda, amode, Ksz);
            *(u32*)&As[row][2 * kp] = aw;
            u32 bw = 0;
            if (pidx < Kh) bw = Bp[(size_t)(n0 + row) * Kh + pidx];
            *(u32*)&Bs[row][2 * kp] = bw;
        }
        __syncthreads();

        bf16x8 af = *(const bf16x8*)&As[wv * 16 + lm][quad * 8];
#pragma unroll
        for (int nt = 0; nt < 4; ++nt) {
            bf16x8 bf = *(const bf16x8*)&Bs[nt * 16 + lm][quad * 8];
            acc[nt] = __builtin_amdgcn_mfma_f32_16x16x32_bf16(af, bf, acc[nt], 0, 0, 0);
        }
        __syncthreads();
    }

#pragma unroll
    for (int nt = 0; nt < 4; ++nt) {
#pragma unroll
        for (int r = 0; r < 4; ++r) {
            int m = m0 + wv * 16 + quad * 4 + r;
            if (m >= Msz) continue;
            int n = n0 + nt * 16 + lm;
            float v = acc[nt][r] + bias1[n] + (bias2 ? bias2[n] : 0.f);
            if (relu) v = fmaxf(v, 0.f);
            if (cmode == 0) {
                Cf[(size_t)m * ldc + n] = v;
            } else if (cmode == 1) {
                int b = m / L_, t = m - b * L_;
                Cf[((size_t)(b * 128 + n)) * L_ + t] = v;
            } else if (cmode == 2) {
                int b = m / L_, t = m - b * L_;
                Cf[((size_t)(t * 8 + b)) * ldc + n] = v;
            } else {
                Cb[(size_t)m * ldc + n] = (u16)f2bf_rne(v);
            }
        }
    }
}

// ======================= fused q/k/cnt projection GEMM (bf16 h1b A, packed B) ==================
__global__ __launch_bounds__(256) void gemm_qkv(
    const u16* __restrict__ h1b,
    const u32* __restrict__ qwp, const u32* __restrict__ kwp, const u32* __restrict__ cwp,
    const float* __restrict__ qb, const float* __restrict__ kb, const float* __restrict__ cb,
    float* __restrict__ qo, float* __restrict__ ko, float* __restrict__ co)
{
    __shared__ u16 As[64][40];
    __shared__ u16 Bs[64][40];

    int tid = threadIdx.x;
    int which = blockIdx.y >> 3;
    int m0 = blockIdx.x * 64, n0 = (blockIdx.y & 7) * 64;
    const u32* Bp = which == 0 ? qwp : (which == 1 ? kwp : cwp);
    const float* bias = which == 0 ? qb : (which == 1 ? kb : cb);
    float* Cf = which == 0 ? qo : (which == 1 ? ko : co);

    int wv = tid >> 6, lane = tid & 63;
    int lm = lane & 15, quad = lane >> 4;
    int kp = tid & 15, rw = tid >> 4;

    f32x4 acc[4];
#pragma unroll
    for (int nt = 0; nt < 4; ++nt)
#pragma unroll
        for (int r = 0; r < 4; ++r) acc[nt][r] = 0.f;

    for (int k0 = 0; k0 < 512; k0 += 32) {
#pragma unroll
        for (int i = 0; i < 4; ++i) {
            int row = rw + 16 * i;
            int k = k0 + 2 * kp;
            int m = m0 + row;
            u32 aw = 0;
            if (m < M_) {
                int b = m / L_, t = m - b * L_;
                aw = *(const u32*)(h1b + ((size_t)(t * 8 + b)) * 512 + k);
            }
            *(u32*)&As[row][2 * kp] = aw;
            *(u32*)&Bs[row][2 * kp] = Bp[(size_t)(n0 + row) * 256 + (k0 >> 1) + kp];
        }
        __syncthreads();

        bf16x8 af = *(const bf16x8*)&As[wv * 16 + lm][quad * 8];
#pragma unroll
        for (int nt = 0; nt < 4; ++nt) {
            bf16x8 bf = *(const bf16x8*)&Bs[nt * 16 + lm][quad * 8];
            acc[nt] = __builtin_amdgcn_mfma_f32_16x16x32_bf16(af, bf, acc[nt], 0, 0, 0);
        }
        __syncthreads();
    }

#pragma unroll
    for (int nt = 0; nt < 4; ++nt) {
#pragma unroll
        for (int r = 0; r < 4; ++r) {
            int m = m0 + wv * 16 + quad * 4 + r;
            if (m >= M_) continue;
            int n = n0 + nt * 16 + lm;
            Cf[(size_t)m * 512 + n] = acc[nt][r] + bias[n];
        }
    }
}

// ======================= subject embedding concat (bf16) =======================
__global__ __launch_bounds__(256) void emb_kernel(const float* __restrict__ semb,
                                                  const int* __restrict__ subj,
                                                  u16* __restrict__ x2b)
{
    int idx = blockIdx.x * 256 + threadIdx.x;
    if (idx >= M_ * 64) return;
    int m = idx >> 6, e = idx & 63;
    int b = m / L_;
    x2b[(size_t)m * CE_ + 512 + e] = (u16)f2bf_rne(semb[subj[b] * 64 + e]);
}

// ======================= generic weight pack: fp32 [N][K] -> bf16 pairs [N][K/2] ================
__global__ __launch_bounds__(256) void pack_b(const float* __restrict__ W, u32* __restrict__ P,
                                              int N, int K)
{
    int gid = blockIdx.x * 256 + threadIdx.x;
    int Kh = K >> 1;
    if (gid >= N * Kh) return;
    int n = gid / Kh, p = gid - n * Kh;
    int k = 2 * p;
    u32 lo = f2bf_rne(W[(size_t)n * K + k]);
    u32 hi = f2bf_rne(W[(size_t)n * K + k + 1]);
    P[gid] = lo | (hi << 16);
}

// ======================= fused post-weight pack: qw/kw/cw/fcw (512x512) + outw (128x512) ========
// Destination is one contiguous region: [4 x 131072][outw 32768] words.
__global__ __launch_bounds__(256) void pack_post(const float* __restrict__ qw,
                                                 const float* __restrict__ kw,
                                                 const float* __restrict__ cw,
                                                 const float* __restrict__ fcw,
                                                 const float* __restrict__ outw,
                                                 u32* __restrict__ P)
{
    int gid = blockIdx.x * 256 + threadIdx.x;   // 557056 total
    if (gid >= 557056) return;
    const float* W;
    int local;
    if (gid < 524288) {
        int wsel = gid >> 17;
        W = wsel == 0 ? qw : (wsel == 1 ? kw : (wsel == 2 ? cw : fcw));
        local = gid & 131071;
    } else {
        W = outw;
        local = gid - 524288;
    }
    int n = local >> 8, p = local & 255;
    int k = 2 * p;
    u32 lo = f2bf_rne(W[(size_t)n * 512 + k]);
    u32 hi = f2bf_rne(W[(size_t)n * 512 + k + 1]);
    P[gid] = lo | (hi << 16);
}

// ======================= w2 pack with k-reorder: k' = kk*512 + ci =======================
__global__ __launch_bounds__(256) void pack_w2k(const float* __restrict__ W, u32* __restrict__ P)
{
    int gid = blockIdx.x * 256 + threadIdx.x;   // 512*1024
    int n = gid >> 10, p = gid & 1023;
    int kk = p >> 8, ci = (2 * p) & 511;
    u32 lo = f2bf_rne(W[(size_t)n * 2048 + ci * 4 + kk]);
    u32 hi = f2bf_rne(W[(size_t)n * 2048 + ci * 4 + 4 + kk]);
    P[gid] = lo | (hi << 16);
}

// ======================= fused LSTM weight pack: Whh0/Wih1/Whh1 in one launch ===================
__global__ __launch_bounds__(256) void pack_w3(const float* __restrict__ W0,
                                               const float* __restrict__ W1,
                                               const float* __restrict__ W2,
                                               u32* __restrict__ P)   // P0|P1|P2 contiguous
{
    int gid3 = blockIdx.x * 256 + threadIdx.x;  // 3*524288
    int src = gid3 >> 19;
    int gid = gid3 & 524287;
    const float* W = src == 0 ? W0 : (src == 1 ? W1 : W2);
    int r = gid & 1, lane = (gid >> 1) & 63, i2 = (gid >> 7) & 1;
    int g = (gid >> 8) & 3, j = gid >> 10;
    int row = g * 512 + j;
    int c0 = 4 * (lane + 64 * i2) + 2 * r;
    u32 lo = f2bf_rne(W[(size_t)row * 512 + c0]);
    u32 hi = f2bf_rne(W[(size_t)row * 512 + c0 + 1]);
    P[gid3] = lo | (hi << 16);
}

// ======================= fused 2-layer LSTM step (R10 structure + h1b mirror) ==================
__global__ __launch_bounds__(256, 1) void lstm_step_fused(
    const float* __restrict__ pre0,
    const u32* __restrict__ P0,
    const u32* __restrict__ P1,
    const u32* __restrict__ P2,
    const float* __restrict__ bih1,
    const float* __restrict__ bhh1,
    float* __restrict__ h0seq,
    float* __restrict__ h1seq,
    u16* __restrict__ h1b,
    float* __restrict__ c0st, float* __restrict__ c1st,
    int t)
{
    int layer = blockIdx.x >> 7;
    int blk = blockIdx.x & 127;
    if (layer == 0 && t >= L_) return;
    if (layer == 1 && t == 0) return;
    int tt = layer ? (t - 1) : t;

    int tid = threadIdx.x;
    int l  = tid & 63;
    int rg = tid >> 6;
    int j = blk * 4 + rg;

    __shared__ float4 hA4[1024];
    __shared__ float4 hB4[1024];
    __shared__ float part[4 * 8 * 33];
    __shared__ float gates[4 * 33];

    const u32* wA = (layer ? P2 : P0) + (size_t)j * 1024;
    uint2 wra[8], wrb[8];
#pragma unroll
    for (int i2 = 0; i2 < 2; ++i2)
#pragma unroll
        for (int g = 0; g < 4; ++g)
            wra[i2 * 4 + g] = *(const uint2*)&wA[(g * 2 + i2) * 128 + l * 2];
    if (layer) {
        const u32* wB = P1 + (size_t)j * 1024;
#pragma unroll
        for (int i2 = 0; i2 < 2; ++i2)
#pragma unroll
            for (int g = 0; g < 4; ++g)
                wrb[i2 * 4 + g] = *(const uint2*)&wB[(g * 2 + i2) * 128 + l * 2];
    }
    float mypre = 0.f;
    if (tid < 128) {
        int fw = tid >> 5, fb = tid & 7;
        int grow = ((tid & 31) >> 3) * 512 + blk * 4 + fw;
        mypre = layer ? (bih1[grow] + bhh1[grow])
                      : pre0[((size_t)(tt * 8 + fb)) * 2048 + grow];
    }

    if (tt == 0) {
#pragma unroll
        for (int i = 0; i < 4; ++i)
            hA4[tid + 256 * i] = make_float4(0.f, 0.f, 0.f, 0.f);
    } else {
        const float4* src = (const float4*)((layer ? h1seq : h0seq) + (size_t)(tt - 1) * 4096);
#pragma unroll
        for (int i = 0; i < 4; ++i)
            hA4[tid + 256 * i] = src[tid + 256 * i];
    }
    if (layer) {
        const float4* src = (const float4*)(h0seq + (size_t)tt * 4096);
#pragma unroll
        for (int i = 0; i < 4; ++i)
            hB4[tid + 256 * i] = src[tid + 256 * i];
    }
    __syncthreads();

    float acc[4][8];
#pragma unroll
    for (int g = 0; g < 4; ++g)
#pragma unroll
        for (int b = 0; b < 8; ++b) acc[g][b] = 0.f;

#pragma unroll
    for (int i2 = 0; i2 < 2; ++i2) {
        int cq = l + 64 * i2;
        float4 hv[8];
#pragma unroll
        for (int b = 0; b < 8; ++b) hv[b] = hA4[b * 128 + cq];
#pragma unroll
        for (int g = 0; g < 4; ++g) {
            uint2 ww = wra[i2 * 4 + g];
            float w0 = __uint_as_float(ww.x << 16);
            float w1 = __uint_as_float(ww.x & 0xffff0000u);
            float w2 = __uint_as_float(ww.y << 16);
            float w3 = __uint_as_float(ww.y & 0xffff0000u);
#pragma unroll
            for (int b = 0; b < 8; ++b)
                acc[g][b] = fmaf(w0, hv[b].x, fmaf(w1, hv[b].y,
                            fmaf(w2, hv[b].z, fmaf(w3, hv[b].w, acc[g][b]))));
        }
    }
    if (layer) {
#pragma unroll
        for (int i2 = 0; i2 < 2; ++i2) {
            int cq = l + 64 * i2;
            float4 hv[8];
#pragma unroll
            for (int b = 0; b < 8; ++b) hv[b] = hB4[b * 128 + cq];
#pragma unroll
            for (int g = 0; g < 4; ++g) {
                uint2 ww = wrb[i2 * 4 + g];
                float w0 = __uint_as_float(ww.x << 16);
                float w1 = __uint_as_float(ww.x & 0xffff0000u);
                float w2 = __uint_as_float(ww.y << 16);
                float w3 = __uint_as_float(ww.y & 0xffff0000u);
#pragma unroll
                for (int b = 0; b < 8; ++b)
                    acc[g][b] = fmaf(w0, hv[b].x, fmaf(w1, hv[b].y,
                                fmaf(w2, hv[b].z, fmaf(w3, hv[b].w, acc[g][b]))));
            }
        }
    }

#pragma unroll
    for (int m = 8; m <= 32; m <<= 1)
#pragma unroll
        for (int g = 0; g < 4; ++g)
#pragma unroll
            for (int b = 0; b < 8; ++b)
                acc[g][b] += __shfl_xor(acc[g][b], m);
    if (l < 8) {
#pragma unroll
        for (int g = 0; g < 4; ++g)
#pragma unroll
            for (int b = 0; b < 8; ++b)
                part[(rg * 8 + l) * 33 + g * 8 + b] = acc[g][b];
    }
    __syncthreads();

    if (tid < 128) {
        int w = tid >> 5, x = tid & 31;
        float s = 0.f;
#pragma unroll
        for (int p = 0; p < 8; ++p) s += part[(w * 8 + p) * 33 + x];
        gates[w * 33 + x] = s + mypre;
    }
    __syncthreads();

    if (tid < 32) {
        int w = tid >> 3, b = tid & 7;
        float gi = gates[w * 33 + 0 * 8 + b];
        float gf = gates[w * 33 + 1 * 8 + b];
        float gg = gates[w * 33 + 2 * 8 + b];
        float go = gates[w * 33 + 3 * 8 + b];
        float* cst = layer ? c1st : c0st;
        int ji = blk * 4 + w;
        int ci = b * 512 + ji;
        float cprev = (tt == 0) ? 0.f : cst[ci];
        float si = 1.f / (1.f + expf(-gi));
        float sf = 1.f / (1.f + expf(-gf));
        float so = 1.f / (1.f + expf(-go));
        float cn = sf * cprev + si * tanhf(gg);
        cst[ci] = cn;
        float hv = so * tanhf(cn);
        float* hout = layer ? h1seq : h0seq;
        hout[((size_t)tt * 8 + b) * 512 + ji] = hv;
        if (layer) h1b[((size_t)tt * 8 + b) * 512 + ji] = (u16)f2bf_rne(hv);
    }
}

// ======================= banded attention (radius 50), bf16 out =======================
__global__ __launch_bounds__(128) void attn_kernel(const float* __restrict__ q,
                                                   const float* __restrict__ k,
                                                   const float* __restrict__ cnt,
                                                   const float* __restrict__ rel,
                                                   u16* __restrict__ outb)
{
    int t = blockIdx.x, h = blockIdx.y, b = blockIdx.z;
    int s_lo = max(0, t - R_), s_hi = min(L_ - 1, t + R_);
    int W = s_hi - s_lo + 1;
    int tid = threadIdx.x;

    __shared__ float qrow[64];
    __shared__ float dots[104];
    __shared__ float red[128];

    const float* qp = q + ((size_t)(b * L_ + t) * C_ + h * D_);
    if (tid < 64) qrow[tid] = qp[tid];
    __syncthreads();

    if (tid < W) {
        int s = s_lo + tid;
        const float* kp = k + ((size_t)(b * L_ + s) * C_ + h * D_);
        const float* rp = rel + (R_ + t - s) * D_;
        float acc = 0.f;
#pragma unroll 8
        for (int d = 0; d < 64; ++d)
            acc += qrow[d] * (kp[d] + 0.3f * rp[d]);
        dots[tid] = acc;
    }
    __syncthreads();

    red[tid] = (tid < W) ? dots[tid] : -INFINITY;
    __syncthreads();
    for (int s = 64; s > 0; s >>= 1) {
        if (tid < s) red[tid] = fmaxf(red[tid], red[tid + s]);
        __syncthreads();
    }
    float mx = red[0];
    __syncthreads();
    float e = 0.f;
    if (tid < W) { e = expf(dots[tid] - mx); dots[tid] = e; }
    red[tid] = e;
    __syncthreads();
    for (int s = 64; s > 0; s >>= 1) {
        if (tid < s) red[tid] += red[tid + s];
        __syncthreads();
    }
    float inv = 1.f / red[0];
    if (tid < W) dots[tid] *= inv;
    __syncthreads();

    if (tid < 64) {
        float acc = 0.f;
        const float* cb = cnt + ((size_t)(b * L_ + s_lo) * C_ + h * D_ + tid);
        const float* rb = rel + (R_ + t - s_lo) * D_ + tid;
        for (int i = 0; i < W; ++i)
            acc += dots[i] * (cb[(size_t)i * C_] + 0.3f * rb[-i * D_]);
        outb[(size_t)(b * L_ + t) * C_ + h * D_ + tid] = (u16)f2bf_rne(acc);
    }
}

// ======================= BatchNorm sums (coalesced, atomic) =======================
__global__ __launch_bounds__(512) void bn_sum(const float* __restrict__ fcout, float* __restrict__ stats)
{
    int c = threadIdx.x;
    float s = 0.f, ss = 0.f;
    for (int m = blockIdx.x; m < M_; m += 32) {
        float v = fcout[(size_t)m * 512 + c];
        s += v; ss += v * v;
    }
    atomicAdd(&stats[c], s);
    atomicAdd(&stats[512 + c], ss);
}

// ======================= BN apply + ReLU*scale + residual -> bf16 xfin =======================
__global__ __launch_bounds__(256) void bn_apply(const float* __restrict__ fcout,
                                                const float* __restrict__ stats,
                                                const float* __restrict__ bng, const float* __restrict__ bnb,
                                                const float* __restrict__ ascl,
                                                const float* __restrict__ h1tm,
                                                u16* __restrict__ xfinb)
{
    int idx = blockIdx.x * 256 + threadIdx.x;
    if (idx >= M_ * 512) return;
    int c = idx & 511;
    int m = idx >> 9;
    int b = m / L_, t = m - b * L_;
    float mean = stats[c] * (1.f / (float)M_);
    float var = stats[512 + c] * (1.f / (float)M_) - mean * mean;
    float rs = rsqrtf(fmaxf(var, 0.f) + 1e-5f);
    float v = (fcout[idx] - mean) * rs * bng[c] + bnb[c];
    v = fmaxf(v, 0.f) * ascl[c];
    xfinb[idx] = (u16)f2bf_rne(h1tm[((size_t)(t * 8 + b)) * 512 + c] + v);
}

// ======================= host launch =======================
extern "C" void kernel_launch(void* const* d_in, const int* in_sizes, int n_in,
                              void* d_out, int out_size, void* d_ws, size_t ws_size,
                              hipStream_t stream)
{
    const float* meg  = (const float*)d_in[0];
    const float* w1   = (const float*)d_in[1];
    const float* b1   = (const float*)d_in[2];
    const float* w2   = (const float*)d_in[3];
    const float* b2   = (const float*)d_in[4];
    const float* semb = (const float*)d_in[5];
    const float* Wih0 = (const float*)d_in[6];
    const float* Whh0 = (const float*)d_in[7];
    const float* bih0 = (const float*)d_in[8];
    const float* bhh0 = (const float*)d_in[9];
    const float* Wih1 = (const float*)d_in[10];
    const float* Whh1 = (const float*)d_in[11];
    const float* bih1 = (const float*)d_in[12];
    const float* bhh1 = (const float*)d_in[13];
    const float* qw   = (const float*)d_in[14];
    const float* qb   = (const float*)d_in[15];
    const float* kw   = (const float*)d_in[16];
    const float* kb   = (const float*)d_in[17];
    const float* cw   = (const float*)d_in[18];
    const float* cbi  = (const float*)d_in[19];
    const float* rel  = (const float*)d_in[20];
    const float* fcw  = (const float*)d_in[21];
    const float* fcb  = (const float*)d_in[22];
    const float* bng  = (const float*)d_in[23];
    const float* bnb  = (const float*)d_in[24];
    const float* ascl = (const float*)d_in[25];
    const float* outw = (const float*)d_in[26];
    const float* outb = (const float*)d_in[27];
    const int* subj = (const int*)d_in[28];
    float* out = (float*)d_out;

    float* ws = (float*)d_ws;
    // ---- arena (float-slot offsets), phase-overlaid ----
    // conv phase:
    u16*   x1b   = (u16*)(ws + 0);          // [8200][512] bf16
    u32*   w1p   = (u32*)(ws + 6562304);    // 512x546
    u32*   w2p   = (u32*)(ws + 6841856);    // 512x1024
    u16*   x2b   = (u16*)(ws + 4198400);    // [4104][576] bf16
    u32*   wih0p = (u32*)(ws + 14967296);   // 2048x288
    // LSTM phase:
    u32*   P0    = (u32*)(ws + 0);          // P0|P1|P2 contiguous (pack_w3)
    u32*   P1    = (u32*)(ws + 524288);
    u32*   P2    = (u32*)(ws + 1048576);
    float* c0    = ws + 1572864;
    float* c1    = ws + 1576960;
    float* pre0  = ws + 6562304;            // [(t*8+b)][2048] fp32
    float* h0    = ws + 14967296;           // [t][b][c] fp32
    float* h1    = ws + 17068544;
    u16*   h1b   = (u16*)(ws + 19169792);   // bf16 mirror
    // post-LSTM phase:
    float* qb_f  = ws + 0;
    float* kb_f  = ws + 2101248;
    float* cb_f  = ws + 4202496;
    u16*   attno = (u16*)(ws + 6562304);    // bf16, over dead pre0
    float* fco   = ws + 8663552;
    float* stats = ws + 10764800;
    u32*   qwp   = (u32*)(ws + 10765824);   // contiguous: qwp|kwp|cwp|fcwp|outwp
    u32*   kwp   = (u32*)(ws + 10896896);
    u32*   cwp   = (u32*)(ws + 11027968);
    u32*   fcwp  = (u32*)(ws + 11159040);
    u32*   outwp = (u32*)(ws + 11290112);
    u16*   xfinb = (u16*)(ws + 19169792);   // bf16, overwrites dead h1b

    auto gemm = [&](const void* A, const u32* Bp, const float* bi1, const float* bi2,
                    float* Cf, u16* Cb, int Msz, int Nsz, int Ksz,
                    int lda, int ldc, int amode, int cmode, int relu) {
        dim3 g((Msz + 63) / 64, Nsz / 64);
        gemm_kernel<<<g, 256, 0, stream>>>(A, Bp, bi1, bi2, Cf, Cb,
                                           Msz, Nsz, Ksz, lda, ldc, amode, cmode, relu);
    };

    // ---- pack conv weights ----
    pack_b<<<(512 * 546 + 255) / 256, 256, 0, stream>>>(w1, w1p, 512, 1092);
    pack_w2k<<<2048, 256, 0, stream>>>(w2, w2p);

    // conv1 -> x1b bf16 [b*1025+t][512], relu
    gemm(meg, w1p, b1, nullptr, nullptr, x1b, M1_, 512, K1_, 0, 512, 2, 3, 1);
    // conv2 -> x2b bf16 [b*513+t][576] cols 0..511, relu
    gemm(x1b, w2p, b2, nullptr, nullptr, x2b, M_, 512, 2048, 0, CE_, 5, 3, 1);
    // subject embedding bf16 -> cols 512..575
    emb_kernel<<<(M_ * 64 + 255) / 256, 256, 0, stream>>>(semb, subj, x2b);

    // ---- pack LSTM (one launch) + pre0 weights ----
    pack_w3<<<6144, 256, 0, stream>>>(Whh0, Wih1, Whh1, P0);
    pack_b<<<(2048 * 288 + 255) / 256, 256, 0, stream>>>(Wih0, wih0p, 2048, 576);

    // layer-0 x-projection (bf16 A, packed B, time-major fp32 out, both biases)
    gemm(x2b, wih0p, bih0, bhh0, pre0, nullptr, M_, 2048, CE_, CE_, 2048, 6, 2, 0);

    // fused 2-layer LSTM: 514 launches
    for (int t = 0; t <= L_; ++t)
        lstm_step_fused<<<256, 256, 0, stream>>>(pre0, P0, P1, P2, bih1, bhh1,
                                                 h0, h1, h1b, c0, c1, t);

    // ---- pack post weights (one launch) + zero bn stats ----
    pack_post<<<(557056 + 255) / 256, 256, 0, stream>>>(qw, kw, cw, fcw, outw, qwp);
    hipMemsetAsync(stats, 0, 1024 * sizeof(float), stream);

    // fused q/k/cnt projections (bf16 h1b)
    gemm_qkv<<<dim3((M_ + 63) / 64, 24), 256, 0, stream>>>(h1b, qwp, kwp, cwp, qb, kb, cbi,
                                                           qb_f, kb_f, cb_f);

    attn_kernel<<<dim3(L_, H_, B_), 128, 0, stream>>>(qb_f, kb_f, cb_f, rel, attno);

    // fc (bf16 attno A) + BN(train) + relu*scale + residual -> xfinb bf16
    gemm(attno, fcwp, fcb, nullptr, fco, nullptr, M_, 512, 512, 512, 512, 6, 0, 0);
    bn_sum<<<32, 512, 0, stream>>>(fco, stats);
    bn_apply<<<(M_ * 512 + 255) / 256, 256, 0, stream>>>(fco, stats, bng, bnb, ascl, h1, xfinb);

    // final projection -> d_out [b][128][t] fp32 (bf16 xfin A)
    gemm(xfinb, outwp, outb, nullptr, out, nullptr, M_, 128, 512, 512, 0, 6, 1, 0);
}